// Round 10
// baseline (1909.958 us; speedup 1.0000x reference)
//
#include <hip/hip_runtime.h>

#define SEQ_ 2111
#define NSTD 3.16227766e-3f
#define GBLK 16
#define GCOLS 32

typedef unsigned short u16;
typedef unsigned int   u32;
typedef __attribute__((ext_vector_type(8))) short bf16x8;
typedef __attribute__((ext_vector_type(4))) float f32x4;
typedef __attribute__((ext_vector_type(4))) u32   u32x4;

__device__ __forceinline__ float bf2f(u16 u){ return __uint_as_float(((u32)u)<<16); }
__device__ __forceinline__ u16 f2bf(float f){
  u32 u = __float_as_uint(f);
  u += 0x7fffu + ((u>>16)&1u);
  return (u16)(u>>16);
}
__device__ __forceinline__ float wsum(float v){
  #pragma unroll
  for (int off=32; off>0; off>>=1) v += __shfl_xor(v, off, 64);
  return v;
}
__device__ __forceinline__ void gload16(const u16* g, u16* l){
  __builtin_amdgcn_global_load_lds((const __attribute__((address_space(1))) void*)g,
                                   (__attribute__((address_space(3))) void*)l, 16, 0, 0);
}

// ---------------------------------------------------------------- transpose+cvt
__global__ void tcvt_k(const float* __restrict__ in, u16* __restrict__ out,
                       int R, int C, size_t inZ, size_t outZ)
{
  __shared__ float tile[32][33];
  int z = blockIdx.z;
  const float* inz = in + inZ*(size_t)z;
  u16* outz = out + outZ*(size_t)z;
  int c0 = blockIdx.x*32, r0 = blockIdx.y*32;
  int lx = threadIdx.x & 31, ly = threadIdx.x >> 5;
  #pragma unroll
  for (int i=0;i<32;i+=8) tile[ly+i][lx] = inz[(size_t)(r0+ly+i)*C + c0+lx];
  __syncthreads();
  #pragma unroll
  for (int i=0;i<32;i+=8) outz[(size_t)(c0+ly+i)*R + r0+lx] = f2bf(tile[lx][ly+i]);
}

__global__ void cvt_k(const float* __restrict__ in, u16* __restrict__ out, int n){
  for (int i = blockIdx.x*blockDim.x + threadIdx.x; i<n; i += gridDim.x*blockDim.x)
    out[i] = f2bf(in[i]);
}

// ---------------------------------------------------------------- hf (Burg LPC + LSF + rms)
__device__ __forceinline__ float evalG(const float* c, int m, float w){
  float x = cosf(w);
  float b1=0.f, b2=0.f;
  for (int d=m; d>=1; --d){ float bb = c[d] + 2.f*x*b1 - b2; b2=b1; b1=bb; }
  return c[0] + x*b1 - b2;
}

__global__ __launch_bounds__(64) void hf_k(const int* __restrict__ seq,
                                           const float* __restrict__ noise,
                                           float* __restrict__ hf)
{
  __shared__ float xs[64], as_[16];
  __shared__ float cc[2][9];
  __shared__ float brk[2][16][2];
  __shared__ int   cnt[2];
  __shared__ float rts[16];
  const float PI = 3.14159265358979f;
  int lane = threadIdx.x;
  int s = blockIdx.x, b = s>>5, f = s&31;
  float q = (float)seq[b*SEQ_ + f*64 + lane];
  float xw = (q*(1.f/64.f) - 2.f + NSTD*noise[(size_t)s*64+lane])
             * (0.5f - 0.5f*cosf((2.f*PI/63.f)*(float)lane));
  xs[lane] = xw;
  if (lane < 2) cnt[lane] = 0;
  __syncthreads();

  float fwd = (lane<63) ? xs[lane+1] : 0.f;
  float bwd = (lane<63) ? xw : 0.f;
  float den = wsum(fwd*fwd + bwd*bwd) + 1e-12f;
  float a = (lane==0) ? 1.f : 0.f;
  for (int i=0;i<15;i++){
    float kk = -2.f * wsum(bwd*fwd) / den;
    float ap = __shfl(a, (i+1-lane)&15, 64);
    if (lane < 16) a += kk*ap;
    float fn = fwd + kk*bwd;
    float bn = bwd + kk*fwd;
    int last = 62 - i;
    float f0 = __shfl(fn, 0, 64);
    float bl = __shfl(bn, last, 64);
    den = (1.f - kk*kk)*den - f0*f0 - bl*bl;
    float fx = __shfl(fn, (lane+1)&63, 64);
    fwd = (lane < last) ? fx : 0.f;
    bwd = (lane < last) ? bn : 0.f;
  }
  if (lane < 16) as_[lane] = a;
  __syncthreads();

  float racc = 0.f;
  #pragma unroll
  for (int k=0;k<16;k++) if (lane >= k) racc += as_[k]*xs[lane-k];
  float rms = sqrtf(wsum(racc*racc) * (1.f/64.f));

  if (lane == 0){
    float a1[17];
    #pragma unroll
    for (int i=0;i<16;i++) a1[i] = as_[i];
    a1[16] = 0.f;
    float p[15];
    for (int k=0;k<15;k++){
      float P1 = a1[k] - a1[16-k];
      p[k] = P1 + (k>=2 ? p[k-2] : 0.f);
    }
    cc[0][0] = p[7];
    for (int d=1; d<=7; d++) cc[0][d] = 2.f*p[7-d];
    cc[1][0] = 2.f*a1[8];
    for (int d=1; d<=8; d++) cc[1][d] = 2.f*(a1[8-d] + a1[8+d]);
  }
  __syncthreads();

  const float STEP = PI/2048.f;
  for (int pq=0; pq<2; pq++){
    int m = 7+pq;
    int i0 = lane*32;
    float fp = evalG(&cc[pq][0], m, (float)i0*STEP);
    for (int ii=1; ii<=32; ii++){
      float fc = evalG(&cc[pq][0], m, (float)(i0+ii)*STEP);
      if (fp*fc < 0.f){
        int id = atomicAdd(&cnt[pq], 1);
        if (id < 16){ brk[pq][id][0] = (float)(i0+ii-1)*STEP; brk[pq][id][1] = (float)(i0+ii)*STEP; }
      }
      fp = fc;
    }
  }
  if (lane < 16) rts[lane] = 3.2f;
  __syncthreads();

  int pq = (lane>=16) ? 1 : 0;
  int ridx = pq ? (lane-16) : lane;
  int nexp = pq ? 8 : 7;
  if (lane < 32 && ridx < nexp && ridx < cnt[pq]){
    int m = 7+pq;
    float lo = brk[pq][ridx][0], hi = brk[pq][ridx][1];
    float flo = evalG(&cc[pq][0], m, lo);
    for (int it=0; it<28; ++it){
      float mid = 0.5f*(lo+hi);
      float fm = evalG(&cc[pq][0], m, mid);
      if ((flo<0.f)==(fm<0.f)){ lo=mid; flo=fm; } else hi=mid;
    }
    rts[pq ? 7+ridx : ridx] = 0.5f*(lo+hi);
  }
  __syncthreads();
  if (lane == 0){
    for (int i=1;i<15;i++){
      float v = rts[i]; int j=i-1;
      while (j>=0 && rts[j]>v){ rts[j+1]=rts[j]; j--; }
      rts[j+1]=v;
    }
  }
  __syncthreads();
  if (lane < 15) hf[(size_t)s*16 + lane] = rts[lane];
  if (lane == 0) hf[(size_t)s*16 + 15] = rms;
}

// ---------------------------------------------------------------- small input-proj kernels (write t-major rows)
__global__ __launch_bounds__(512) void inp_top_k(const int* __restrict__ seq, const float* __restrict__ hf,
  const float* __restrict__ Win, const float* __restrict__ Whf, const float* __restrict__ bin,
  u16* __restrict__ outp)
{
  __shared__ float pv[64], hv[16];
  int m = blockIdx.x, b = m>>5, f = m&31, n = threadIdx.x;
  if (n < 64) pv[n] = (float)seq[b*SEQ_ + f*64 + n]*(1.f/64.f) - 2.f;
  else if (n < 80) hv[n-64] = hf[(size_t)m*16 + (n-64)];
  __syncthreads();
  float s = bin[n];
  #pragma unroll 8
  for (int k=0;k<64;k++) s += pv[k]*Win[k*512+n];
  #pragma unroll
  for (int k=0;k<16;k++) s += hv[k]*Whf[k*512+n];
  outp[((size_t)(f*64 + b))*512 + n] = f2bf(s);   // t-major
}

__global__ __launch_bounds__(512) void inp_bot_k(const int* __restrict__ seq, const float* __restrict__ hf,
  const float* __restrict__ cond, const float* __restrict__ Win, const float* __restrict__ Whf,
  const float* __restrict__ bin, u16* __restrict__ outp)
{
  __shared__ float pv[16], hv[16];
  int m = blockIdx.x, b = m>>7, tb = m&127, n = threadIdx.x;
  if (n < 16) pv[n] = (float)seq[b*SEQ_ + 48 + tb*16 + n]*(1.f/64.f) - 2.f;
  else if (n < 32) hv[n-16] = hf[((size_t)(b*32 + (tb>>2)))*16 + (n-16)];
  __syncthreads();
  float s = bin[n] + cond[(size_t)m*512 + n];
  #pragma unroll
  for (int k=0;k<16;k++) s += pv[k]*Win[k*512+n];
  #pragma unroll
  for (int k=0;k<16;k++) s += hv[k]*Whf[k*512+n];
  outp[((size_t)(tb*64 + b))*512 + n] = f2bf(s);  // t-major
}

// ---------------------------------------------------------------- MFMA GEMM 256x256 tile, 8 waves: out = A(MxK)*BT(NxK)^T
// 2-phase, global_load_lds width=16 staging. LDS rows padded to 40 u16 (80B):
// granule q=g%5 of row g/5; q==4 is pad (re-loads granule 0, harmless).
template<int BIAS, int RELU, int OUTBF>
__global__ __launch_bounds__(512) void gemm256(
    const u16* __restrict__ A, const u16* __restrict__ BT,
    const float* __restrict__ bias, void* __restrict__ outp,
    int M, int N, int K, size_t bStrideBT, size_t bStrideOutBytes)
{
  (void)M;
  __shared__ __align__(16) u16 As[256][40];
  __shared__ __align__(16) u16 Bs[256][40];
  const u16* BTz = BT + bStrideBT * (size_t)blockIdx.z;
  int tid = threadIdx.x, lane = tid & 63, wv = tid >> 6;
  int l15 = lane & 15, lq = lane >> 4;
  int wr = (wv>>2)*128, wc = (wv&3)*64;     // wave owns 128x64 of the 256x256 tile
  int rowA0 = blockIdx.x*256, colB0 = blockIdx.y*256;

  // 40 staging instructions per k-step (20 A + 20 B); wave wv owns j = wv+8s, s=0..4.
  const u16* srcp[5];
  u16* ldsp[5];
  #pragma unroll
  for (int s=0;s<5;s++){
    int j = wv + s*8;
    int i = (j<20) ? j : j-20;
    int g = i*64 + lane;
    int row = g/5, q = g - row*5;
    int col16 = (q==4) ? 0 : q*8;
    if (j<20){ srcp[s] = A   + (size_t)(rowA0+row)*K + col16; ldsp[s] = &As[0][0] + i*512; }
    else     { srcp[s] = BTz + (size_t)(colB0+row)*K + col16; ldsp[s] = &Bs[0][0] + i*512; }
  }

  f32x4 acc[8][4];
  #pragma unroll
  for (int i=0;i<8;i++)
    #pragma unroll
    for (int j=0;j<4;j++) acc[i][j] = (f32x4){0.f,0.f,0.f,0.f};

  for (int k0=0; k0<K; k0+=32){
    __syncthreads();
    #pragma unroll
    for (int s=0;s<5;s++) gload16(srcp[s] + k0, ldsp[s]);
    __syncthreads();   // drains vmcnt (LDS ready) + barrier
    bf16x8 af[8], bfr[4];
    #pragma unroll
    for (int m=0;m<8;m++) af[m]  = *(const bf16x8*)&As[wr + m*16 + l15][lq*8];
    #pragma unroll
    for (int n=0;n<4;n++) bfr[n] = *(const bf16x8*)&Bs[wc + n*16 + l15][lq*8];
    #pragma unroll
    for (int m=0;m<8;m++)
      #pragma unroll
      for (int n=0;n<4;n++)
        acc[m][n] = __builtin_amdgcn_mfma_f32_16x16x32_bf16(af[m], bfr[n], acc[m][n], 0,0,0);
  }

  char* outz = (char*)outp + bStrideOutBytes * (size_t)blockIdx.z;
  #pragma unroll
  for (int n=0;n<4;n++){
    int col = colB0 + wc + n*16 + l15;
    float bv = BIAS ? bias[col] : 0.f;
    #pragma unroll
    for (int m=0;m<8;m++){
      #pragma unroll
      for (int r=0;r<4;r++){
        int row = rowA0 + wr + m*16 + lq*4 + r;
        float v = acc[m][n][r] + bv;
        if (RELU) v = v>0.f ? v : 0.f;
        if (OUTBF) ((u16*)outz)[(size_t)row*N + col] = f2bf(v);
        else       ((float*)outz)[(size_t)row*N + col] = v;
      }
    }
  }
}

// ---------------------------------------------------------------- GRU: 16 blocks x 32 cols, MALL-coherent h/flags (sc0 sc1)
// Round-7 verified version: no cache-maintenance ops; h + flags written through
// to / read from the device coherence point with sc0 sc1 vector ops.
__global__ __launch_bounds__(256) void gru_k(const float* __restrict__ gx,
                                             const u16* __restrict__ WhT,
                                             u16* __restrict__ hout,
                                             u16* __restrict__ hbuf,
                                             int* __restrict__ flags, int T, int base)
{
  __shared__ __align__(16) u16 Ws[96][520];
  int tid = threadIdx.x, lane = tid & 63, wv = tid >> 6;
  int l15 = lane & 15, lq = lane >> 4;
  int U0 = blockIdx.x*GCOLS;
  for (int i = tid; i < 96*64; i += 256){
    int lc = i >> 6, kk = (i & 63)*8;
    int g = lc >> 5, j = lc & 31;
    *(bf16x8*)&Ws[lc][kk] = *(const bf16x8*)(WhT + ((size_t)(g*512 + U0 + j))*512 + kk);
  }
  float hreg[2][4] = {{0.f,0.f,0.f,0.f},{0.f,0.f,0.f,0.f}};
  int row0 = wv*16;
  __syncthreads();

  float gxr[3][2][4];
  #pragma unroll
  for (int r=0;r<4;r++){
    const float* gp = gx + ((size_t)(row0 + lq*4 + r))*1536;
    #pragma unroll
    for (int nf=0;nf<2;nf++){
      int u = U0 + nf*16 + l15;
      gxr[0][nf][r] = gp[u]; gxr[1][nf][r] = gp[512+u]; gxr[2][nf][r] = gp[1024+u];
    }
  }

  for (int t=0; t<T; ++t){
    f32x4 acc[3][2];
    #pragma unroll
    for (int g=0;g<3;g++)
      #pragma unroll
      for (int nf=0;nf<2;nf++) acc[g][nf] = (f32x4){0.f,0.f,0.f,0.f};

    if (t > 0){
      if (wv == 0){
        const int* fp = flags + (lane & 15)*32;
        int target = base + t;
        while (true){
          int v;
          asm volatile("global_load_dword %0, %1, off sc0 sc1\n\ts_waitcnt vmcnt(0)"
                       : "=v"(v) : "v"(fp) : "memory");
          if (__all(v >= target)) break;
        }
      }
      __syncthreads();
      const u16* hsrc = hbuf + (size_t)(t&1)*(64*512);
      const u16* hp = hsrc + (size_t)(row0 + l15)*512 + lq*8;
      bf16x8 af[16];
      asm volatile(
        "global_load_dwordx4 %0,  %16, off sc0 sc1\n\t"
        "global_load_dwordx4 %1,  %16, off offset:64 sc0 sc1\n\t"
        "global_load_dwordx4 %2,  %16, off offset:128 sc0 sc1\n\t"
        "global_load_dwordx4 %3,  %16, off offset:192 sc0 sc1\n\t"
        "global_load_dwordx4 %4,  %16, off offset:256 sc0 sc1\n\t"
        "global_load_dwordx4 %5,  %16, off offset:320 sc0 sc1\n\t"
        "global_load_dwordx4 %6,  %16, off offset:384 sc0 sc1\n\t"
        "global_load_dwordx4 %7,  %16, off offset:448 sc0 sc1\n\t"
        "global_load_dwordx4 %8,  %16, off offset:512 sc0 sc1\n\t"
        "global_load_dwordx4 %9,  %16, off offset:576 sc0 sc1\n\t"
        "global_load_dwordx4 %10, %16, off offset:640 sc0 sc1\n\t"
        "global_load_dwordx4 %11, %16, off offset:704 sc0 sc1\n\t"
        "global_load_dwordx4 %12, %16, off offset:768 sc0 sc1\n\t"
        "global_load_dwordx4 %13, %16, off offset:832 sc0 sc1\n\t"
        "global_load_dwordx4 %14, %16, off offset:896 sc0 sc1\n\t"
        "global_load_dwordx4 %15, %16, off offset:960 sc0 sc1"
        : "=v"(af[0]), "=v"(af[1]), "=v"(af[2]), "=v"(af[3]),
          "=v"(af[4]), "=v"(af[5]), "=v"(af[6]), "=v"(af[7]),
          "=v"(af[8]), "=v"(af[9]), "=v"(af[10]), "=v"(af[11]),
          "=v"(af[12]), "=v"(af[13]), "=v"(af[14]), "=v"(af[15])
        : "v"(hp) : "memory");
      asm volatile("s_waitcnt vmcnt(0)" ::: "memory");
      __builtin_amdgcn_sched_barrier(0);   // rule #18
      #pragma unroll
      for (int k=0;k<16;k++){
        #pragma unroll
        for (int g=0;g<3;g++){
          #pragma unroll
          for (int nf=0;nf<2;nf++){
            bf16x8 bf_ = *(const bf16x8*)&Ws[g*GCOLS + nf*16 + l15][k*32 + lq*8];
            acc[g][nf] = __builtin_amdgcn_mfma_f32_16x16x32_bf16(af[k], bf_, acc[g][nf], 0,0,0);
          }
        }
      }
    }

    u16* hdst = hbuf + (size_t)((t+1)&1)*(64*512);
    u16 hb[2][4];
    u32 hv[8];
    #pragma unroll
    for (int nf=0;nf<2;nf++){
      #pragma unroll
      for (int r=0;r<4;r++){
        float rg = 1.f/(1.f + __expf(-(acc[0][nf][r] + gxr[0][nf][r])));
        float zg = 1.f/(1.f + __expf(-(acc[1][nf][r] + gxr[1][nf][r])));
        float ng = tanhf(gxr[2][nf][r] + rg*acc[2][nf][r]);
        float hn = (1.f - zg)*ng + zg*hreg[nf][r];
        hreg[nf][r] = hn;
        hb[nf][r] = f2bf(hn);
        hv[nf*4+r] = hb[nf][r];
      }
    }
    {
      u16* sp_ = hdst + (size_t)(row0 + lq*4)*512 + U0 + l15;
      asm volatile(
        "global_store_short %8, %0, off sc0 sc1\n\t"
        "global_store_short %8, %1, off offset:1024 sc0 sc1\n\t"
        "global_store_short %8, %2, off offset:2048 sc0 sc1\n\t"
        "global_store_short %8, %3, off offset:3072 sc0 sc1\n\t"
        "global_store_short %8, %4, off offset:32 sc0 sc1\n\t"
        "global_store_short %8, %5, off offset:1056 sc0 sc1\n\t"
        "global_store_short %8, %6, off offset:2080 sc0 sc1\n\t"
        "global_store_short %8, %7, off offset:3104 sc0 sc1"
        :: "v"(hv[0]), "v"(hv[1]), "v"(hv[2]), "v"(hv[3]),
           "v"(hv[4]), "v"(hv[5]), "v"(hv[6]), "v"(hv[7]), "v"(sp_)
        : "memory");
    }
    asm volatile("s_waitcnt vmcnt(0)" ::: "memory");
    __syncthreads();
    if (tid == 0){
      int val = base + t + 1;
      asm volatile("global_store_dword %0, %1, off sc0 sc1"
                   :: "v"(flags + blockIdx.x*32), "v"(val) : "memory");
    }
    #pragma unroll
    for (int nf=0;nf<2;nf++){
      int u = U0 + nf*16 + l15;
      #pragma unroll
      for (int r=0;r<4;r++)
        hout[(((size_t)(row0 + lq*4 + r))*T + t)*512 + u] = hb[nf][r];
    }
    if (t+1 < T){
      #pragma unroll
      for (int r=0;r<4;r++){
        const float* gp = gx + ((size_t)(t+1)*64 + row0 + lq*4 + r)*1536;
        #pragma unroll
        for (int nf=0;nf<2;nf++){
          int u = U0 + nf*16 + l15;
          gxr[0][nf][r] = gp[u]; gxr[1][nf][r] = gp[512+u]; gxr[2][nf][r] = gp[1024+u];
        }
      }
    }
  }
}

// ---------------------------------------------------------------- conv via lookup table + cond + bias + relu
__global__ __launch_bounds__(256) void conv_k(const int* __restrict__ seq, const u16* __restrict__ Ttab,
  const u16* __restrict__ cond, const float* __restrict__ bconv, u16* __restrict__ h1, int chunk)
{
  int sub = threadIdx.x >> 6, lane = threadIdx.x & 63;
  int lrow = blockIdx.x*4 + sub;
  int g = chunk*32768 + lrow;
  int b = g >> 11, t = g & 2047;
  const int* sp = seq + b*SEQ_ + 48 + t;
  int o = lane*8;
  float a[8];
  bf16x8 cs = *(const bf16x8*)(cond + (size_t)lrow*512 + o);
  #pragma unroll
  for (int j=0;j<8;j++) a[j] = bf2f((u16)cs[j]) + bconv[o+j];
  #pragma unroll
  for (int w=0;w<16;w++){
    int q = sp[w];
    bf16x8 tv = *(const bf16x8*)(Ttab + ((size_t)(w*256+q))*512 + o);
    #pragma unroll
    for (int j=0;j<8;j++) a[j] += bf2f((u16)tv[j]);
  }
  u16 res[8];
  #pragma unroll
  for (int j=0;j<8;j++) res[j] = f2bf(a[j] > 0.f ? a[j] : 0.f);
  *(bf16x8*)(h1 + (size_t)lrow*512 + o) = *(const bf16x8*)res;
}

// ---------------------------------------------------------------- launcher
extern "C" void kernel_launch(void* const* d_in, const int* in_sizes, int n_in,
                              void* d_out, int out_size, void* d_ws, size_t ws_size,
                              hipStream_t stream)
{
  (void)in_sizes; (void)n_in; (void)out_size; (void)ws_size;
  const int*   seq     = (const int*)d_in[0];
  const float* noise   = (const float*)d_in[2];
  const float* W_in_top= (const float*)d_in[3];
  const float* W_hf_top= (const float*)d_in[4];
  const float* b_in_top= (const float*)d_in[5];
  const float* Wx_top  = (const float*)d_in[6];
  const float* bx_top  = (const float*)d_in[7];
  const float* Wh_top  = (const float*)d_in[8];
  const float* W_up_top= (const float*)d_in[9];
  const float* W_in_bot= (const float*)d_in[10];
  const float* W_hf_bot= (const float*)d_in[11];
  const float* b_in_bot= (const float*)d_in[12];
  const float* Wx_bot  = (const float*)d_in[13];
  const float* bx_bot  = (const float*)d_in[14];
  const float* Wh_bot  = (const float*)d_in[15];
  const float* W_up_bot= (const float*)d_in[16];
  const float* embed   = (const float*)d_in[17];
  const float* W_conv  = (const float*)d_in[18];
  const float* b_conv  = (const float*)d_in[19];
  const float* W1      = (const float*)d_in[20];
  const float* b1      = (const float*)d_in[21];
  const float* W2      = (const float*)d_in[22];
  const float* b2      = (const float*)d_in[23];
  const float* W_out   = (const float*)d_in[24];
  const float* b_out   = (const float*)d_in[25];
  float* outF = (float*)d_out;
  char* ws = (char*)d_ws;

  size_t off = 0;
  auto alloc = [&](size_t bytes){ size_t o = off; off = (off + bytes + 255) & ~(size_t)255; return o; };
  const size_t oHF   = alloc((size_t)2048*16*4);
  const size_t oWxtT = alloc((size_t)1536*512*2);
  const size_t oWhtT = alloc((size_t)1536*512*2);
  const size_t oWxtB = alloc((size_t)1536*512*2);
  const size_t oWhtB = alloc((size_t)1536*512*2);
  const size_t oWupT = alloc((size_t)2048*512*2);
  const size_t oWupB = alloc((size_t)8192*512*2);
  const size_t oW1T  = alloc((size_t)512*512*2);
  const size_t oW2T  = alloc((size_t)512*512*2);
  const size_t oWoT  = alloc((size_t)256*512*2);
  const size_t oEmb  = alloc((size_t)256*256*2);
  const size_t oWcT  = alloc((size_t)16*512*256*2);
  const size_t oTtab = alloc((size_t)16*256*512*2);
  const size_t oHbot = alloc((size_t)8192*512*2);
  const size_t oGruH = alloc((size_t)2*64*512*2);   // h double buffer
  const size_t oBar  = alloc(4096);                 // per-block flag cachelines
  const size_t SCR   = off;
  const size_t MB = 1u<<20;
  const size_t oInpT = SCR;
  const size_t oGxT  = SCR + 4*MB;
  const size_t oHtop = SCR;
  const size_t oCond = SCR + 4*MB;
  const size_t oInpB = SCR + 24*MB;
  const size_t oGxB  = SCR + 36*MB;
  const size_t oCndC = SCR;
  const size_t oH1   = SCR + 34*MB;
  const size_t oH2   = SCR + 68*MB;
  const size_t oH3   = SCR + 102*MB;

  dim3 b256(256), b512(512), b64(64);

  // ---- weight prep
  tcvt_k<<<dim3(48,16,1),b256,0,stream>>>(Wx_top,(u16*)(ws+oWxtT),512,1536,0,0);
  tcvt_k<<<dim3(48,16,1),b256,0,stream>>>(Wh_top,(u16*)(ws+oWhtT),512,1536,0,0);
  tcvt_k<<<dim3(48,16,1),b256,0,stream>>>(Wx_bot,(u16*)(ws+oWxtB),512,1536,0,0);
  tcvt_k<<<dim3(48,16,1),b256,0,stream>>>(Wh_bot,(u16*)(ws+oWhtB),512,1536,0,0);
  tcvt_k<<<dim3(64,16,1),b256,0,stream>>>(W_up_top,(u16*)(ws+oWupT),512,2048,0,0);
  tcvt_k<<<dim3(256,16,1),b256,0,stream>>>(W_up_bot,(u16*)(ws+oWupB),512,8192,0,0);
  tcvt_k<<<dim3(16,16,1),b256,0,stream>>>(W1,(u16*)(ws+oW1T),512,512,0,0);
  tcvt_k<<<dim3(16,16,1),b256,0,stream>>>(W2,(u16*)(ws+oW2T),512,512,0,0);
  tcvt_k<<<dim3(8,16,1),b256,0,stream>>>(W_out,(u16*)(ws+oWoT),512,256,0,0);
  tcvt_k<<<dim3(16,8,16),b256,0,stream>>>(W_conv,(u16*)(ws+oWcT),256,512,(size_t)256*512,(size_t)512*256);
  cvt_k<<<dim3(64),b256,0,stream>>>(embed,(u16*)(ws+oEmb),256*256);

  // ---- hf features
  hf_k<<<dim3(2048),b64,0,stream>>>(seq, noise, (float*)(ws+oHF));

  // ---- barrier flags init (flags carry across both GRUs via `base`)
  hipMemsetAsync(ws+oBar, 0, 4096, stream);

  // ---- top frame-level path
  inp_top_k<<<dim3(2048),b512,0,stream>>>(seq,(const float*)(ws+oHF),W_in_top,W_hf_top,b_in_top,(u16*)(ws+oInpT));
  gemm256<1,0,0><<<dim3(8,6,1),b512,0,stream>>>((const u16*)(ws+oInpT),(const u16*)(ws+oWxtT),bx_top,(void*)(ws+oGxT),2048,1536,512,0,0);
  gru_k<<<dim3(GBLK),b256,0,stream>>>((const float*)(ws+oGxT),(const u16*)(ws+oWhtT),(u16*)(ws+oHtop),(u16*)(ws+oGruH),(int*)(ws+oBar),32,0);
  gemm256<0,0,0><<<dim3(8,8,1),b512,0,stream>>>((const u16*)(ws+oHtop),(const u16*)(ws+oWupT),nullptr,(void*)(ws+oCond),2048,2048,512,0,0);

  // ---- bottom frame-level path
  inp_bot_k<<<dim3(8192),b512,0,stream>>>(seq,(const float*)(ws+oHF),(const float*)(ws+oCond),W_in_bot,W_hf_bot,b_in_bot,(u16*)(ws+oInpB));
  gemm256<1,0,0><<<dim3(32,6,1),b512,0,stream>>>((const u16*)(ws+oInpB),(const u16*)(ws+oWxtB),bx_bot,(void*)(ws+oGxB),8192,1536,512,0,0);
  gru_k<<<dim3(GBLK),b256,0,stream>>>((const float*)(ws+oGxB),(const u16*)(ws+oWhtB),(u16*)(ws+oHbot),(u16*)(ws+oGruH),(int*)(ws+oBar),128,32);

  // ---- conv lookup table T[w] = embed @ W_conv[w]
  gemm256<0,0,1><<<dim3(1,2,16),b512,0,stream>>>((const u16*)(ws+oEmb),(const u16*)(ws+oWcT),nullptr,(void*)(ws+oTtab),
                                                 256,512,256,(size_t)512*256,(size_t)256*512*2);

  // ---- sample-level tail, 4 chunks of 32768 rows
  for (int c=0;c<4;c++){
    const u16* hbc = (const u16*)(ws+oHbot) + (size_t)c*2048*512;
    gemm256<0,0,1><<<dim3(8,32,1),b512,0,stream>>>(hbc,(const u16*)(ws+oWupB),nullptr,(void*)(ws+oCndC),2048,8192,512,0,0);
    conv_k<<<dim3(8192),b256,0,stream>>>(seq,(const u16*)(ws+oTtab),(const u16*)(ws+oCndC),b_conv,(u16*)(ws+oH1),c);
    gemm256<1,1,1><<<dim3(128,2,1),b512,0,stream>>>((const u16*)(ws+oH1),(const u16*)(ws+oW1T),b1,(void*)(ws+oH2),32768,512,512,0,0);
    gemm256<1,1,1><<<dim3(128,2,1),b512,0,stream>>>((const u16*)(ws+oH2),(const u16*)(ws+oW2T),b2,(void*)(ws+oH3),32768,512,512,0,0);
    gemm256<1,0,0><<<dim3(128,1,1),b512,0,stream>>>((const u16*)(ws+oH3),(const u16*)(ws+oWoT),b_out,(void*)(outF + (size_t)c*32768*256),32768,256,512,0,0);
  }
}

// Round 11
// 1719.446 us; speedup vs baseline: 1.1108x; 1.1108x over previous
//
#include <hip/hip_runtime.h>

#define SEQ_ 2111
#define NSTD 3.16227766e-3f
#define GBLK 16
#define GCOLS 32

typedef unsigned short u16;
typedef unsigned int   u32;
typedef __attribute__((ext_vector_type(8))) short bf16x8;
typedef __attribute__((ext_vector_type(4))) float f32x4;
typedef __attribute__((ext_vector_type(4))) u32   u32x4;

__device__ __forceinline__ float bf2f(u16 u){ return __uint_as_float(((u32)u)<<16); }
__device__ __forceinline__ u16 f2bf(float f){
  u32 u = __float_as_uint(f);
  u += 0x7fffu + ((u>>16)&1u);
  return (u16)(u>>16);
}
__device__ __forceinline__ float wsum(float v){
  #pragma unroll
  for (int off=32; off>0; off>>=1) v += __shfl_xor(v, off, 64);
  return v;
}
__device__ __forceinline__ void gload16(const u16* g, u16* l){
  __builtin_amdgcn_global_load_lds((const __attribute__((address_space(1))) void*)g,
                                   (__attribute__((address_space(3))) void*)l, 16, 0, 0);
}

// ---------------------------------------------------------------- transpose+cvt
__global__ void tcvt_k(const float* __restrict__ in, u16* __restrict__ out,
                       int R, int C, size_t inZ, size_t outZ)
{
  __shared__ float tile[32][33];
  int z = blockIdx.z;
  const float* inz = in + inZ*(size_t)z;
  u16* outz = out + outZ*(size_t)z;
  int c0 = blockIdx.x*32, r0 = blockIdx.y*32;
  int lx = threadIdx.x & 31, ly = threadIdx.x >> 5;
  #pragma unroll
  for (int i=0;i<32;i+=8) tile[ly+i][lx] = inz[(size_t)(r0+ly+i)*C + c0+lx];
  __syncthreads();
  #pragma unroll
  for (int i=0;i<32;i+=8) outz[(size_t)(c0+ly+i)*R + r0+lx] = f2bf(tile[lx][ly+i]);
}

__global__ void cvt_k(const float* __restrict__ in, u16* __restrict__ out, int n){
  for (int i = blockIdx.x*blockDim.x + threadIdx.x; i<n; i += gridDim.x*blockDim.x)
    out[i] = f2bf(in[i]);
}

// ---------------------------------------------------------------- hf (Burg LPC + LSF + rms)
__device__ __forceinline__ float evalG(const float* c, int m, float w){
  float x = cosf(w);
  float b1=0.f, b2=0.f;
  for (int d=m; d>=1; --d){ float bb = c[d] + 2.f*x*b1 - b2; b2=b1; b1=bb; }
  return c[0] + x*b1 - b2;
}

__global__ __launch_bounds__(64) void hf_k(const int* __restrict__ seq,
                                           const float* __restrict__ noise,
                                           float* __restrict__ hf)
{
  __shared__ float xs[64], as_[16];
  __shared__ float cc[2][9];
  __shared__ float brk[2][16][2];
  __shared__ int   cnt[2];
  __shared__ float rts[16];
  const float PI = 3.14159265358979f;
  int lane = threadIdx.x;
  int s = blockIdx.x, b = s>>5, f = s&31;
  float q = (float)seq[b*SEQ_ + f*64 + lane];
  float xw = (q*(1.f/64.f) - 2.f + NSTD*noise[(size_t)s*64+lane])
             * (0.5f - 0.5f*cosf((2.f*PI/63.f)*(float)lane));
  xs[lane] = xw;
  if (lane < 2) cnt[lane] = 0;
  __syncthreads();

  float fwd = (lane<63) ? xs[lane+1] : 0.f;
  float bwd = (lane<63) ? xw : 0.f;
  float den = wsum(fwd*fwd + bwd*bwd) + 1e-12f;
  float a = (lane==0) ? 1.f : 0.f;
  for (int i=0;i<15;i++){
    float kk = -2.f * wsum(bwd*fwd) / den;
    float ap = __shfl(a, (i+1-lane)&15, 64);
    if (lane < 16) a += kk*ap;
    float fn = fwd + kk*bwd;
    float bn = bwd + kk*fwd;
    int last = 62 - i;
    float f0 = __shfl(fn, 0, 64);
    float bl = __shfl(bn, last, 64);
    den = (1.f - kk*kk)*den - f0*f0 - bl*bl;
    float fx = __shfl(fn, (lane+1)&63, 64);
    fwd = (lane < last) ? fx : 0.f;
    bwd = (lane < last) ? bn : 0.f;
  }
  if (lane < 16) as_[lane] = a;
  __syncthreads();

  float racc = 0.f;
  #pragma unroll
  for (int k=0;k<16;k++) if (lane >= k) racc += as_[k]*xs[lane-k];
  float rms = sqrtf(wsum(racc*racc) * (1.f/64.f));

  if (lane == 0){
    float a1[17];
    #pragma unroll
    for (int i=0;i<16;i++) a1[i] = as_[i];
    a1[16] = 0.f;
    float p[15];
    for (int k=0;k<15;k++){
      float P1 = a1[k] - a1[16-k];
      p[k] = P1 + (k>=2 ? p[k-2] : 0.f);
    }
    cc[0][0] = p[7];
    for (int d=1; d<=7; d++) cc[0][d] = 2.f*p[7-d];
    cc[1][0] = 2.f*a1[8];
    for (int d=1; d<=8; d++) cc[1][d] = 2.f*(a1[8-d] + a1[8+d]);
  }
  __syncthreads();

  const float STEP = PI/2048.f;
  for (int pq=0; pq<2; pq++){
    int m = 7+pq;
    int i0 = lane*32;
    float fp = evalG(&cc[pq][0], m, (float)i0*STEP);
    for (int ii=1; ii<=32; ii++){
      float fc = evalG(&cc[pq][0], m, (float)(i0+ii)*STEP);
      if (fp*fc < 0.f){
        int id = atomicAdd(&cnt[pq], 1);
        if (id < 16){ brk[pq][id][0] = (float)(i0+ii-1)*STEP; brk[pq][id][1] = (float)(i0+ii)*STEP; }
      }
      fp = fc;
    }
  }
  if (lane < 16) rts[lane] = 3.2f;
  __syncthreads();

  int pq = (lane>=16) ? 1 : 0;
  int ridx = pq ? (lane-16) : lane;
  int nexp = pq ? 8 : 7;
  if (lane < 32 && ridx < nexp && ridx < cnt[pq]){
    int m = 7+pq;
    float lo = brk[pq][ridx][0], hi = brk[pq][ridx][1];
    float flo = evalG(&cc[pq][0], m, lo);
    for (int it=0; it<28; ++it){
      float mid = 0.5f*(lo+hi);
      float fm = evalG(&cc[pq][0], m, mid);
      if ((flo<0.f)==(fm<0.f)){ lo=mid; flo=fm; } else hi=mid;
    }
    rts[pq ? 7+ridx : ridx] = 0.5f*(lo+hi);
  }
  __syncthreads();
  if (lane == 0){
    for (int i=1;i<15;i++){
      float v = rts[i]; int j=i-1;
      while (j>=0 && rts[j]>v){ rts[j+1]=rts[j]; j--; }
      rts[j+1]=v;
    }
  }
  __syncthreads();
  if (lane < 15) hf[(size_t)s*16 + lane] = rts[lane];
  if (lane == 0) hf[(size_t)s*16 + 15] = rms;
}

// ---------------------------------------------------------------- small input-proj kernels (write t-major rows)
__global__ __launch_bounds__(512) void inp_top_k(const int* __restrict__ seq, const float* __restrict__ hf,
  const float* __restrict__ Win, const float* __restrict__ Whf, const float* __restrict__ bin,
  u16* __restrict__ outp)
{
  __shared__ float pv[64], hv[16];
  int m = blockIdx.x, b = m>>5, f = m&31, n = threadIdx.x;
  if (n < 64) pv[n] = (float)seq[b*SEQ_ + f*64 + n]*(1.f/64.f) - 2.f;
  else if (n < 80) hv[n-64] = hf[(size_t)m*16 + (n-64)];
  __syncthreads();
  float s = bin[n];
  #pragma unroll 8
  for (int k=0;k<64;k++) s += pv[k]*Win[k*512+n];
  #pragma unroll
  for (int k=0;k<16;k++) s += hv[k]*Whf[k*512+n];
  outp[((size_t)(f*64 + b))*512 + n] = f2bf(s);   // t-major
}

__global__ __launch_bounds__(512) void inp_bot_k(const int* __restrict__ seq, const float* __restrict__ hf,
  const float* __restrict__ cond, const float* __restrict__ Win, const float* __restrict__ Whf,
  const float* __restrict__ bin, u16* __restrict__ outp)
{
  __shared__ float pv[16], hv[16];
  int m = blockIdx.x, b = m>>7, tb = m&127, n = threadIdx.x;
  if (n < 16) pv[n] = (float)seq[b*SEQ_ + 48 + tb*16 + n]*(1.f/64.f) - 2.f;
  else if (n < 32) hv[n-16] = hf[((size_t)(b*32 + (tb>>2)))*16 + (n-16)];
  __syncthreads();
  float s = bin[n] + cond[(size_t)m*512 + n];
  #pragma unroll
  for (int k=0;k<16;k++) s += pv[k]*Win[k*512+n];
  #pragma unroll
  for (int k=0;k<16;k++) s += hv[k]*Whf[k*512+n];
  outp[((size_t)(tb*64 + b))*512 + n] = f2bf(s);  // t-major
}

// ---------------------------------------------------------------- MFMA GEMM 128x128, BK=64: out = A(MxK)*BT(NxK)^T
// global_load_lds w=16 staging. LDS rows padded to 72 u16 (144B): granule
// q=g%9 of row g/9; q==8 is pad (re-loads granule 0, harmless). 36 staging
// insts per 64-wide k-step (9/wave); two MFMA sub-steps per k-step.
template<int BIAS, int RELU, int OUTBF>
__global__ __launch_bounds__(256) void gemm_bt(
    const u16* __restrict__ A, const u16* __restrict__ BT,
    const float* __restrict__ bias, void* __restrict__ outp,
    int M, int N, int K, size_t bStrideBT, size_t bStrideOutBytes)
{
  (void)M;
  __shared__ __align__(16) u16 As[128][72];
  __shared__ __align__(16) u16 Bs[128][72];
  const u16* BTz = BT + bStrideBT * (size_t)blockIdx.z;
  int tid = threadIdx.x, lane = tid & 63, wv = tid >> 6;
  int l15 = lane & 15, lq = lane >> 4;
  int wr = (wv>>1)*64, wc = (wv&1)*64;
  int rowA0 = blockIdx.x*128, colB0 = blockIdx.y*128;

  const u16* srcp[9];
  u16* ldsp[9];
  #pragma unroll
  for (int s=0;s<9;s++){
    int j = wv + s*4;              // 0..35
    int i = (j<18) ? j : j-18;     // instr index within matrix
    int g = i*64 + lane;           // granule id 0..1151
    int row = g/9, q = g - row*9;
    int col16 = (q==8) ? 0 : q*8;
    if (j<18){ srcp[s] = A   + (size_t)(rowA0+row)*K + col16; ldsp[s] = &As[0][0] + i*512; }
    else     { srcp[s] = BTz + (size_t)(colB0+row)*K + col16; ldsp[s] = &Bs[0][0] + i*512; }
  }

  f32x4 acc[4][4];
  #pragma unroll
  for (int i=0;i<4;i++)
    #pragma unroll
    for (int j=0;j<4;j++) acc[i][j] = (f32x4){0.f,0.f,0.f,0.f};

  for (int k0=0; k0<K; k0+=64){
    __syncthreads();
    #pragma unroll
    for (int s=0;s<9;s++) gload16(srcp[s] + k0, ldsp[s]);
    __syncthreads();   // drains vmcnt (LDS ready) + barrier
    #pragma unroll
    for (int kk=0;kk<2;kk++){
      bf16x8 af[4], bfr[4];
      #pragma unroll
      for (int m=0;m<4;m++) af[m]  = *(const bf16x8*)&As[wr + m*16 + l15][kk*32 + lq*8];
      #pragma unroll
      for (int n=0;n<4;n++) bfr[n] = *(const bf16x8*)&Bs[wc + n*16 + l15][kk*32 + lq*8];
      #pragma unroll
      for (int m=0;m<4;m++)
        #pragma unroll
        for (int n=0;n<4;n++)
          acc[m][n] = __builtin_amdgcn_mfma_f32_16x16x32_bf16(af[m], bfr[n], acc[m][n], 0,0,0);
    }
  }

  char* outz = (char*)outp + bStrideOutBytes * (size_t)blockIdx.z;
  #pragma unroll
  for (int n=0;n<4;n++){
    int col = colB0 + wc + n*16 + l15;
    float bv = BIAS ? bias[col] : 0.f;
    #pragma unroll
    for (int m=0;m<4;m++){
      #pragma unroll
      for (int r=0;r<4;r++){
        int row = rowA0 + wr + m*16 + lq*4 + r;
        float v = acc[m][n][r] + bv;
        if (RELU) v = v>0.f ? v : 0.f;
        if (OUTBF) ((u16*)outz)[(size_t)row*N + col] = f2bf(v);
        else       ((float*)outz)[(size_t)row*N + col] = v;
      }
    }
  }
}

// ---------------------------------------------------------------- GRU: 16 blocks x 32 cols, MALL-coherent h/flags (sc0 sc1)
// Round-7 verified version.
__global__ __launch_bounds__(256) void gru_k(const float* __restrict__ gx,
                                             const u16* __restrict__ WhT,
                                             u16* __restrict__ hout,
                                             u16* __restrict__ hbuf,
                                             int* __restrict__ flags, int T, int base)
{
  __shared__ __align__(16) u16 Ws[96][520];
  int tid = threadIdx.x, lane = tid & 63, wv = tid >> 6;
  int l15 = lane & 15, lq = lane >> 4;
  int U0 = blockIdx.x*GCOLS;
  for (int i = tid; i < 96*64; i += 256){
    int lc = i >> 6, kk = (i & 63)*8;
    int g = lc >> 5, j = lc & 31;
    *(bf16x8*)&Ws[lc][kk] = *(const bf16x8*)(WhT + ((size_t)(g*512 + U0 + j))*512 + kk);
  }
  float hreg[2][4] = {{0.f,0.f,0.f,0.f},{0.f,0.f,0.f,0.f}};
  int row0 = wv*16;
  __syncthreads();

  float gxr[3][2][4];
  #pragma unroll
  for (int r=0;r<4;r++){
    const float* gp = gx + ((size_t)(row0 + lq*4 + r))*1536;
    #pragma unroll
    for (int nf=0;nf<2;nf++){
      int u = U0 + nf*16 + l15;
      gxr[0][nf][r] = gp[u]; gxr[1][nf][r] = gp[512+u]; gxr[2][nf][r] = gp[1024+u];
    }
  }

  for (int t=0; t<T; ++t){
    f32x4 acc[3][2];
    #pragma unroll
    for (int g=0;g<3;g++)
      #pragma unroll
      for (int nf=0;nf<2;nf++) acc[g][nf] = (f32x4){0.f,0.f,0.f,0.f};

    if (t > 0){
      if (wv == 0){
        const int* fp = flags + (lane & 15)*32;
        int target = base + t;
        while (true){
          int v;
          asm volatile("global_load_dword %0, %1, off sc0 sc1\n\ts_waitcnt vmcnt(0)"
                       : "=v"(v) : "v"(fp) : "memory");
          if (__all(v >= target)) break;
        }
      }
      __syncthreads();
      const u16* hsrc = hbuf + (size_t)(t&1)*(64*512);
      const u16* hp = hsrc + (size_t)(row0 + l15)*512 + lq*8;
      bf16x8 af[16];
      asm volatile(
        "global_load_dwordx4 %0,  %16, off sc0 sc1\n\t"
        "global_load_dwordx4 %1,  %16, off offset:64 sc0 sc1\n\t"
        "global_load_dwordx4 %2,  %16, off offset:128 sc0 sc1\n\t"
        "global_load_dwordx4 %3,  %16, off offset:192 sc0 sc1\n\t"
        "global_load_dwordx4 %4,  %16, off offset:256 sc0 sc1\n\t"
        "global_load_dwordx4 %5,  %16, off offset:320 sc0 sc1\n\t"
        "global_load_dwordx4 %6,  %16, off offset:384 sc0 sc1\n\t"
        "global_load_dwordx4 %7,  %16, off offset:448 sc0 sc1\n\t"
        "global_load_dwordx4 %8,  %16, off offset:512 sc0 sc1\n\t"
        "global_load_dwordx4 %9,  %16, off offset:576 sc0 sc1\n\t"
        "global_load_dwordx4 %10, %16, off offset:640 sc0 sc1\n\t"
        "global_load_dwordx4 %11, %16, off offset:704 sc0 sc1\n\t"
        "global_load_dwordx4 %12, %16, off offset:768 sc0 sc1\n\t"
        "global_load_dwordx4 %13, %16, off offset:832 sc0 sc1\n\t"
        "global_load_dwordx4 %14, %16, off offset:896 sc0 sc1\n\t"
        "global_load_dwordx4 %15, %16, off offset:960 sc0 sc1"
        : "=v"(af[0]), "=v"(af[1]), "=v"(af[2]), "=v"(af[3]),
          "=v"(af[4]), "=v"(af[5]), "=v"(af[6]), "=v"(af[7]),
          "=v"(af[8]), "=v"(af[9]), "=v"(af[10]), "=v"(af[11]),
          "=v"(af[12]), "=v"(af[13]), "=v"(af[14]), "=v"(af[15])
        : "v"(hp) : "memory");
      asm volatile("s_waitcnt vmcnt(0)" ::: "memory");
      __builtin_amdgcn_sched_barrier(0);   // rule #18
      #pragma unroll
      for (int k=0;k<16;k++){
        #pragma unroll
        for (int g=0;g<3;g++){
          #pragma unroll
          for (int nf=0;nf<2;nf++){
            bf16x8 bf_ = *(const bf16x8*)&Ws[g*GCOLS + nf*16 + l15][k*32 + lq*8];
            acc[g][nf] = __builtin_amdgcn_mfma_f32_16x16x32_bf16(af[k], bf_, acc[g][nf], 0,0,0);
          }
        }
      }
    }

    u16* hdst = hbuf + (size_t)((t+1)&1)*(64*512);
    u16 hb[2][4];
    u32 hv[8];
    #pragma unroll
    for (int nf=0;nf<2;nf++){
      #pragma unroll
      for (int r=0;r<4;r++){
        float rg = 1.f/(1.f + __expf(-(acc[0][nf][r] + gxr[0][nf][r])));
        float zg = 1.f/(1.f + __expf(-(acc[1][nf][r] + gxr[1][nf][r])));
        float ng = tanhf(gxr[2][nf][r] + rg*acc[2][nf][r]);
        float hn = (1.f - zg)*ng + zg*hreg[nf][r];
        hreg[nf][r] = hn;
        hb[nf][r] = f2bf(hn);
        hv[nf*4+r] = hb[nf][r];
      }
    }
    {
      u16* sp_ = hdst + (size_t)(row0 + lq*4)*512 + U0 + l15;
      asm volatile(
        "global_store_short %8, %0, off sc0 sc1\n\t"
        "global_store_short %8, %1, off offset:1024 sc0 sc1\n\t"
        "global_store_short %8, %2, off offset:2048 sc0 sc1\n\t"
        "global_store_short %8, %3, off offset:3072 sc0 sc1\n\t"
        "global_store_short %8, %4, off offset:32 sc0 sc1\n\t"
        "global_store_short %8, %5, off offset:1056 sc0 sc1\n\t"
        "global_store_short %8, %6, off offset:2080 sc0 sc1\n\t"
        "global_store_short %8, %7, off offset:3104 sc0 sc1"
        :: "v"(hv[0]), "v"(hv[1]), "v"(hv[2]), "v"(hv[3]),
           "v"(hv[4]), "v"(hv[5]), "v"(hv[6]), "v"(hv[7]), "v"(sp_)
        : "memory");
    }
    asm volatile("s_waitcnt vmcnt(0)" ::: "memory");
    __syncthreads();
    if (tid == 0){
      int val = base + t + 1;
      asm volatile("global_store_dword %0, %1, off sc0 sc1"
                   :: "v"(flags + blockIdx.x*32), "v"(val) : "memory");
    }
    #pragma unroll
    for (int nf=0;nf<2;nf++){
      int u = U0 + nf*16 + l15;
      #pragma unroll
      for (int r=0;r<4;r++)
        hout[(((size_t)(row0 + lq*4 + r))*T + t)*512 + u] = hb[nf][r];
    }
    if (t+1 < T){
      #pragma unroll
      for (int r=0;r<4;r++){
        const float* gp = gx + ((size_t)(t+1)*64 + row0 + lq*4 + r)*1536;
        #pragma unroll
        for (int nf=0;nf<2;nf++){
          int u = U0 + nf*16 + l15;
          gxr[0][nf][r] = gp[u]; gxr[1][nf][r] = gp[512+u]; gxr[2][nf][r] = gp[1024+u];
        }
      }
    }
  }
}

// ---------------------------------------------------------------- conv via lookup table + cond + bias + relu
__global__ __launch_bounds__(256) void conv_k(const int* __restrict__ seq, const u16* __restrict__ Ttab,
  const u16* __restrict__ cond, const float* __restrict__ bconv, u16* __restrict__ h1, int chunk)
{
  int sub = threadIdx.x >> 6, lane = threadIdx.x & 63;
  int lrow = blockIdx.x*4 + sub;
  int g = chunk*32768 + lrow;
  int b = g >> 11, t = g & 2047;
  const int* sp = seq + b*SEQ_ + 48 + t;
  int o = lane*8;
  float a[8];
  bf16x8 cs = *(const bf16x8*)(cond + (size_t)lrow*512 + o);
  #pragma unroll
  for (int j=0;j<8;j++) a[j] = bf2f((u16)cs[j]) + bconv[o+j];
  #pragma unroll
  for (int w=0;w<16;w++){
    int q = sp[w];
    bf16x8 tv = *(const bf16x8*)(Ttab + ((size_t)(w*256+q))*512 + o);
    #pragma unroll
    for (int j=0;j<8;j++) a[j] += bf2f((u16)tv[j]);
  }
  u16 res[8];
  #pragma unroll
  for (int j=0;j<8;j++) res[j] = f2bf(a[j] > 0.f ? a[j] : 0.f);
  *(bf16x8*)(h1 + (size_t)lrow*512 + o) = *(const bf16x8*)res;
}

// ---------------------------------------------------------------- launcher
extern "C" void kernel_launch(void* const* d_in, const int* in_sizes, int n_in,
                              void* d_out, int out_size, void* d_ws, size_t ws_size,
                              hipStream_t stream)
{
  (void)in_sizes; (void)n_in; (void)out_size; (void)ws_size;
  const int*   seq     = (const int*)d_in[0];
  const float* noise   = (const float*)d_in[2];
  const float* W_in_top= (const float*)d_in[3];
  const float* W_hf_top= (const float*)d_in[4];
  const float* b_in_top= (const float*)d_in[5];
  const float* Wx_top  = (const float*)d_in[6];
  const float* bx_top  = (const float*)d_in[7];
  const float* Wh_top  = (const float*)d_in[8];
  const float* W_up_top= (const float*)d_in[9];
  const float* W_in_bot= (const float*)d_in[10];
  const float* W_hf_bot= (const float*)d_in[11];
  const float* b_in_bot= (const float*)d_in[12];
  const float* Wx_bot  = (const float*)d_in[13];
  const float* bx_bot  = (const float*)d_in[14];
  const float* Wh_bot  = (const float*)d_in[15];
  const float* W_up_bot= (const float*)d_in[16];
  const float* embed   = (const float*)d_in[17];
  const float* W_conv  = (const float*)d_in[18];
  const float* b_conv  = (const float*)d_in[19];
  const float* W1      = (const float*)d_in[20];
  const float* b1      = (const float*)d_in[21];
  const float* W2      = (const float*)d_in[22];
  const float* b2      = (const float*)d_in[23];
  const float* W_out   = (const float*)d_in[24];
  const float* b_out   = (const float*)d_in[25];
  float* outF = (float*)d_out;
  char* ws = (char*)d_ws;

  size_t off = 0;
  auto alloc = [&](size_t bytes){ size_t o = off; off = (off + bytes + 255) & ~(size_t)255; return o; };
  const size_t oHF   = alloc((size_t)2048*16*4);
  const size_t oWxtT = alloc((size_t)1536*512*2);
  const size_t oWhtT = alloc((size_t)1536*512*2);
  const size_t oWxtB = alloc((size_t)1536*512*2);
  const size_t oWhtB = alloc((size_t)1536*512*2);
  const size_t oWupT = alloc((size_t)2048*512*2);
  const size_t oWupB = alloc((size_t)8192*512*2);
  const size_t oW1T  = alloc((size_t)512*512*2);
  const size_t oW2T  = alloc((size_t)512*512*2);
  const size_t oWoT  = alloc((size_t)256*512*2);
  const size_t oEmb  = alloc((size_t)256*256*2);
  const size_t oWcT  = alloc((size_t)16*512*256*2);
  const size_t oTtab = alloc((size_t)16*256*512*2);
  const size_t oHbot = alloc((size_t)8192*512*2);
  const size_t oGruH = alloc((size_t)2*64*512*2);   // h double buffer
  const size_t oBar  = alloc(4096);                 // per-block flag cachelines
  const size_t SCR   = off;
  const size_t MB = 1u<<20;
  const size_t oInpT = SCR;
  const size_t oGxT  = SCR + 4*MB;
  const size_t oHtop = SCR;
  const size_t oCond = SCR + 4*MB;
  const size_t oInpB = SCR + 24*MB;
  const size_t oGxB  = SCR + 36*MB;
  const size_t oCndC = SCR;
  const size_t oH1   = SCR + 34*MB;
  const size_t oH2   = SCR + 68*MB;
  const size_t oH3   = SCR + 102*MB;

  dim3 b256(256), b512(512), b64(64);

  // ---- weight prep
  tcvt_k<<<dim3(48,16,1),b256,0,stream>>>(Wx_top,(u16*)(ws+oWxtT),512,1536,0,0);
  tcvt_k<<<dim3(48,16,1),b256,0,stream>>>(Wh_top,(u16*)(ws+oWhtT),512,1536,0,0);
  tcvt_k<<<dim3(48,16,1),b256,0,stream>>>(Wx_bot,(u16*)(ws+oWxtB),512,1536,0,0);
  tcvt_k<<<dim3(48,16,1),b256,0,stream>>>(Wh_bot,(u16*)(ws+oWhtB),512,1536,0,0);
  tcvt_k<<<dim3(64,16,1),b256,0,stream>>>(W_up_top,(u16*)(ws+oWupT),512,2048,0,0);
  tcvt_k<<<dim3(256,16,1),b256,0,stream>>>(W_up_bot,(u16*)(ws+oWupB),512,8192,0,0);
  tcvt_k<<<dim3(16,16,1),b256,0,stream>>>(W1,(u16*)(ws+oW1T),512,512,0,0);
  tcvt_k<<<dim3(16,16,1),b256,0,stream>>>(W2,(u16*)(ws+oW2T),512,512,0,0);
  tcvt_k<<<dim3(8,16,1),b256,0,stream>>>(W_out,(u16*)(ws+oWoT),512,256,0,0);
  tcvt_k<<<dim3(16,8,16),b256,0,stream>>>(W_conv,(u16*)(ws+oWcT),256,512,(size_t)256*512,(size_t)512*256);
  cvt_k<<<dim3(64),b256,0,stream>>>(embed,(u16*)(ws+oEmb),256*256);

  // ---- hf features
  hf_k<<<dim3(2048),b64,0,stream>>>(seq, noise, (float*)(ws+oHF));

  // ---- barrier flags init (flags carry across both GRUs via `base`)
  hipMemsetAsync(ws+oBar, 0, 4096, stream);

  // ---- top frame-level path
  inp_top_k<<<dim3(2048),b512,0,stream>>>(seq,(const float*)(ws+oHF),W_in_top,W_hf_top,b_in_top,(u16*)(ws+oInpT));
  gemm_bt<1,0,0><<<dim3(16,12,1),b256,0,stream>>>((const u16*)(ws+oInpT),(const u16*)(ws+oWxtT),bx_top,(void*)(ws+oGxT),2048,1536,512,0,0);
  gru_k<<<dim3(GBLK),b256,0,stream>>>((const float*)(ws+oGxT),(const u16*)(ws+oWhtT),(u16*)(ws+oHtop),(u16*)(ws+oGruH),(int*)(ws+oBar),32,0);
  gemm_bt<0,0,0><<<dim3(16,16,1),b256,0,stream>>>((const u16*)(ws+oHtop),(const u16*)(ws+oWupT),nullptr,(void*)(ws+oCond),2048,2048,512,0,0);

  // ---- bottom frame-level path
  inp_bot_k<<<dim3(8192),b512,0,stream>>>(seq,(const float*)(ws+oHF),(const float*)(ws+oCond),W_in_bot,W_hf_bot,b_in_bot,(u16*)(ws+oInpB));
  gemm_bt<1,0,0><<<dim3(64,12,1),b256,0,stream>>>((const u16*)(ws+oInpB),(const u16*)(ws+oWxtB),bx_bot,(void*)(ws+oGxB),8192,1536,512,0,0);
  gru_k<<<dim3(GBLK),b256,0,stream>>>((const float*)(ws+oGxB),(const u16*)(ws+oWhtB),(u16*)(ws+oHbot),(u16*)(ws+oGruH),(int*)(ws+oBar),128,32);

  // ---- conv lookup table T[w] = embed @ W_conv[w]
  gemm_bt<0,0,1><<<dim3(2,4,16),b256,0,stream>>>((const u16*)(ws+oEmb),(const u16*)(ws+oWcT),nullptr,(void*)(ws+oTtab),
                                                 256,512,256,(size_t)512*256,(size_t)256*512*2);

  // ---- sample-level tail, 4 chunks of 32768 rows
  for (int c=0;c<4;c++){
    const u16* hbc = (const u16*)(ws+oHbot) + (size_t)c*2048*512;
    gemm_bt<0,0,1><<<dim3(16,64,1),b256,0,stream>>>(hbc,(const u16*)(ws+oWupB),nullptr,(void*)(ws+oCndC),2048,8192,512,0,0);
    conv_k<<<dim3(8192),b256,0,stream>>>(seq,(const u16*)(ws+oTtab),(const u16*)(ws+oCndC),b_conv,(u16*)(ws+oH1),c);
    gemm_bt<1,1,1><<<dim3(256,4,1),b256,0,stream>>>((const u16*)(ws+oH1),(const u16*)(ws+oW1T),b1,(void*)(ws+oH2),32768,512,512,0,0);
    gemm_bt<1,1,1><<<dim3(256,4,1),b256,0,stream>>>((const u16*)(ws+oH2),(const u16*)(ws+oW2T),b2,(void*)(ws+oH3),32768,512,512,0,0);
    gemm_bt<1,0,0><<<dim3(256,2,1),b256,0,stream>>>((const u16*)(ws+oH3),(const u16*)(ws+oWoT),b_out,(void*)(outF + (size_t)c*32768*256),32768,256,512,0,0);
  }
}

// Round 12
// 1691.598 us; speedup vs baseline: 1.1291x; 1.0165x over previous
//
#include <hip/hip_runtime.h>

#define SEQ_ 2111
#define NSTD 3.16227766e-3f
#define GBLK 16
#define GCOLS 32

typedef unsigned short u16;
typedef unsigned int   u32;
typedef __attribute__((ext_vector_type(8))) short bf16x8;
typedef __attribute__((ext_vector_type(4))) float f32x4;
typedef __attribute__((ext_vector_type(4))) u32   u32x4;

__device__ __forceinline__ float bf2f(u16 u){ return __uint_as_float(((u32)u)<<16); }
__device__ __forceinline__ u16 f2bf(float f){
  u32 u = __float_as_uint(f);
  u += 0x7fffu + ((u>>16)&1u);
  return (u16)(u>>16);
}
__device__ __forceinline__ float wsum(float v){
  #pragma unroll
  for (int off=32; off>0; off>>=1) v += __shfl_xor(v, off, 64);
  return v;
}
__device__ __forceinline__ void gload16(const u16* g, u16* l){
  __builtin_amdgcn_global_load_lds((const __attribute__((address_space(1))) void*)g,
                                   (__attribute__((address_space(3))) void*)l, 16, 0, 0);
}

// ---------------------------------------------------------------- merged weight prep (1 dispatch)
struct PrepArgs {
  const float *wxt, *wht, *wxb, *whb, *wupt, *wupb, *w1, *w2, *wo, *wc, *emb;
  u16 *owxt, *owht, *owxb, *owhb, *owupt, *owupb, *ow1, *ow2, *owo, *owc, *oemb;
};

__global__ __launch_bounds__(256) void prep_k(PrepArgs a)
{
  __shared__ float tile[32][33];
  int b = blockIdx.x;
  const float* in; u16* out; int R, C, tx, ty;
  if (b < 768)        { int t=b;      in=a.wxt;  out=a.owxt;  R=512; C=1536; tx=t%48;  ty=t/48; }
  else if (b < 1536)  { int t=b-768;  in=a.wht;  out=a.owht;  R=512; C=1536; tx=t%48;  ty=t/48; }
  else if (b < 2304)  { int t=b-1536; in=a.wxb;  out=a.owxb;  R=512; C=1536; tx=t%48;  ty=t/48; }
  else if (b < 3072)  { int t=b-2304; in=a.whb;  out=a.owhb;  R=512; C=1536; tx=t%48;  ty=t/48; }
  else if (b < 4096)  { int t=b-3072; in=a.wupt; out=a.owupt; R=512; C=2048; tx=t%64;  ty=t/64; }
  else if (b < 8192)  { int t=b-4096; in=a.wupb; out=a.owupb; R=512; C=8192; tx=t%256; ty=t/256; }
  else if (b < 8448)  { int t=b-8192; in=a.w1;   out=a.ow1;   R=512; C=512;  tx=t%16;  ty=t/16; }
  else if (b < 8704)  { int t=b-8448; in=a.w2;   out=a.ow2;   R=512; C=512;  tx=t%16;  ty=t/16; }
  else if (b < 8832)  { int t=b-8704; in=a.wo;   out=a.owo;   R=512; C=256;  tx=t%8;   ty=t/8; }
  else if (b < 10880) { int t=b-8832; int z=t>>7; int tt=t&127;
                        in=a.wc + (size_t)z*256*512; out=a.owc + (size_t)z*512*256;
                        R=256; C=512; tx=tt%16; ty=tt/16; }
  else {  // embed cvt: 256 blocks x 256 threads = 65536 elems
    int i = (b-10880)*256 + threadIdx.x;
    a.oemb[i] = f2bf(a.emb[i]);
    return;
  }
  int c0 = tx*32, r0 = ty*32;
  int lx = threadIdx.x & 31, ly = threadIdx.x >> 5;
  #pragma unroll
  for (int i=0;i<32;i+=8) tile[ly+i][lx] = in[(size_t)(r0+ly+i)*C + c0+lx];
  __syncthreads();
  #pragma unroll
  for (int i=0;i<32;i+=8) out[(size_t)(c0+ly+i)*R + r0+lx] = f2bf(tile[lx][ly+i]);
}

// ---------------------------------------------------------------- hf (Burg LPC + LSF + rms)
__device__ __forceinline__ float evalG(const float* c, int m, float w){
  float x = cosf(w);
  float b1=0.f, b2=0.f;
  for (int d=m; d>=1; --d){ float bb = c[d] + 2.f*x*b1 - b2; b2=b1; b1=bb; }
  return c[0] + x*b1 - b2;
}

__global__ __launch_bounds__(64) void hf_k(const int* __restrict__ seq,
                                           const float* __restrict__ noise,
                                           float* __restrict__ hf)
{
  __shared__ float xs[64], as_[16];
  __shared__ float cc[2][9];
  __shared__ float brk[2][16][2];
  __shared__ int   cnt[2];
  __shared__ float rts[16];
  const float PI = 3.14159265358979f;
  int lane = threadIdx.x;
  int s = blockIdx.x, b = s>>5, f = s&31;
  float q = (float)seq[b*SEQ_ + f*64 + lane];
  float xw = (q*(1.f/64.f) - 2.f + NSTD*noise[(size_t)s*64+lane])
             * (0.5f - 0.5f*cosf((2.f*PI/63.f)*(float)lane));
  xs[lane] = xw;
  if (lane < 2) cnt[lane] = 0;
  __syncthreads();

  float fwd = (lane<63) ? xs[lane+1] : 0.f;
  float bwd = (lane<63) ? xw : 0.f;
  float den = wsum(fwd*fwd + bwd*bwd) + 1e-12f;
  float a = (lane==0) ? 1.f : 0.f;
  for (int i=0;i<15;i++){
    float kk = -2.f * wsum(bwd*fwd) / den;
    float ap = __shfl(a, (i+1-lane)&15, 64);
    if (lane < 16) a += kk*ap;
    float fn = fwd + kk*bwd;
    float bn = bwd + kk*fwd;
    int last = 62 - i;
    float f0 = __shfl(fn, 0, 64);
    float bl = __shfl(bn, last, 64);
    den = (1.f - kk*kk)*den - f0*f0 - bl*bl;
    float fx = __shfl(fn, (lane+1)&63, 64);
    fwd = (lane < last) ? fx : 0.f;
    bwd = (lane < last) ? bn : 0.f;
  }
  if (lane < 16) as_[lane] = a;
  __syncthreads();

  float racc = 0.f;
  #pragma unroll
  for (int k=0;k<16;k++) if (lane >= k) racc += as_[k]*xs[lane-k];
  float rms = sqrtf(wsum(racc*racc) * (1.f/64.f));

  if (lane == 0){
    float a1[17];
    #pragma unroll
    for (int i=0;i<16;i++) a1[i] = as_[i];
    a1[16] = 0.f;
    float p[15];
    for (int k=0;k<15;k++){
      float P1 = a1[k] - a1[16-k];
      p[k] = P1 + (k>=2 ? p[k-2] : 0.f);
    }
    cc[0][0] = p[7];
    for (int d=1; d<=7; d++) cc[0][d] = 2.f*p[7-d];
    cc[1][0] = 2.f*a1[8];
    for (int d=1; d<=8; d++) cc[1][d] = 2.f*(a1[8-d] + a1[8+d]);
  }
  __syncthreads();

  const float STEP = PI/2048.f;
  for (int pq=0; pq<2; pq++){
    int m = 7+pq;
    int i0 = lane*32;
    float fp = evalG(&cc[pq][0], m, (float)i0*STEP);
    for (int ii=1; ii<=32; ii++){
      float fc = evalG(&cc[pq][0], m, (float)(i0+ii)*STEP);
      if (fp*fc < 0.f){
        int id = atomicAdd(&cnt[pq], 1);
        if (id < 16){ brk[pq][id][0] = (float)(i0+ii-1)*STEP; brk[pq][id][1] = (float)(i0+ii)*STEP; }
      }
      fp = fc;
    }
  }
  if (lane < 16) rts[lane] = 3.2f;
  __syncthreads();

  int pq = (lane>=16) ? 1 : 0;
  int ridx = pq ? (lane-16) : lane;
  int nexp = pq ? 8 : 7;
  if (lane < 32 && ridx < nexp && ridx < cnt[pq]){
    int m = 7+pq;
    float lo = brk[pq][ridx][0], hi = brk[pq][ridx][1];
    float flo = evalG(&cc[pq][0], m, lo);
    for (int it=0; it<28; ++it){
      float mid = 0.5f*(lo+hi);
      float fm = evalG(&cc[pq][0], m, mid);
      if ((flo<0.f)==(fm<0.f)){ lo=mid; flo=fm; } else hi=mid;
    }
    rts[pq ? 7+ridx : ridx] = 0.5f*(lo+hi);
  }
  __syncthreads();
  if (lane == 0){
    for (int i=1;i<15;i++){
      float v = rts[i]; int j=i-1;
      while (j>=0 && rts[j]>v){ rts[j+1]=rts[j]; j--; }
      rts[j+1]=v;
    }
  }
  __syncthreads();
  if (lane < 15) hf[(size_t)s*16 + lane] = rts[lane];
  if (lane == 0) hf[(size_t)s*16 + 15] = rms;
}

// ---------------------------------------------------------------- small input-proj kernels (write t-major rows)
__global__ __launch_bounds__(512) void inp_top_k(const int* __restrict__ seq, const float* __restrict__ hf,
  const float* __restrict__ Win, const float* __restrict__ Whf, const float* __restrict__ bin,
  u16* __restrict__ outp)
{
  __shared__ float pv[64], hv[16];
  int m = blockIdx.x, b = m>>5, f = m&31, n = threadIdx.x;
  if (n < 64) pv[n] = (float)seq[b*SEQ_ + f*64 + n]*(1.f/64.f) - 2.f;
  else if (n < 80) hv[n-64] = hf[(size_t)m*16 + (n-64)];
  __syncthreads();
  float s = bin[n];
  #pragma unroll 8
  for (int k=0;k<64;k++) s += pv[k]*Win[k*512+n];
  #pragma unroll
  for (int k=0;k<16;k++) s += hv[k]*Whf[k*512+n];
  outp[((size_t)(f*64 + b))*512 + n] = f2bf(s);   // t-major
}

__global__ __launch_bounds__(512) void inp_bot_k(const int* __restrict__ seq, const float* __restrict__ hf,
  const float* __restrict__ cond, const float* __restrict__ Win, const float* __restrict__ Whf,
  const float* __restrict__ bin, u16* __restrict__ outp)
{
  __shared__ float pv[16], hv[16];
  int m = blockIdx.x, b = m>>7, tb = m&127, n = threadIdx.x;
  if (n < 16) pv[n] = (float)seq[b*SEQ_ + 48 + tb*16 + n]*(1.f/64.f) - 2.f;
  else if (n < 32) hv[n-16] = hf[((size_t)(b*32 + (tb>>2)))*16 + (n-16)];
  __syncthreads();
  float s = bin[n] + cond[(size_t)m*512 + n];
  #pragma unroll
  for (int k=0;k<16;k++) s += pv[k]*Win[k*512+n];
  #pragma unroll
  for (int k=0;k<16;k++) s += hv[k]*Whf[k*512+n];
  outp[((size_t)(tb*64 + b))*512 + n] = f2bf(s);  // t-major
}

// ---------------------------------------------------------------- MFMA GEMM 128x128, BK=64: out = A(MxK)*BT(NxK)^T
// global_load_lds w=16 staging; LDS rows 72 u16 (144B): granule q=g%9, q==8 pad.
template<int BIAS, int RELU, int OUTBF>
__global__ __launch_bounds__(256) void gemm_bt(
    const u16* __restrict__ A, const u16* __restrict__ BT,
    const float* __restrict__ bias, void* __restrict__ outp,
    int M, int N, int K, size_t bStrideBT, size_t bStrideOutBytes)
{
  (void)M;
  __shared__ __align__(16) u16 As[128][72];
  __shared__ __align__(16) u16 Bs[128][72];
  const u16* BTz = BT + bStrideBT * (size_t)blockIdx.z;
  int tid = threadIdx.x, lane = tid & 63, wv = tid >> 6;
  int l15 = lane & 15, lq = lane >> 4;
  int wr = (wv>>1)*64, wc = (wv&1)*64;
  int rowA0 = blockIdx.x*128, colB0 = blockIdx.y*128;

  const u16* srcp[9];
  u16* ldsp[9];
  #pragma unroll
  for (int s=0;s<9;s++){
    int j = wv + s*4;
    int i = (j<18) ? j : j-18;
    int g = i*64 + lane;
    int row = g/9, q = g - row*9;
    int col16 = (q==8) ? 0 : q*8;
    if (j<18){ srcp[s] = A   + (size_t)(rowA0+row)*K + col16; ldsp[s] = &As[0][0] + i*512; }
    else     { srcp[s] = BTz + (size_t)(colB0+row)*K + col16; ldsp[s] = &Bs[0][0] + i*512; }
  }

  f32x4 acc[4][4];
  #pragma unroll
  for (int i=0;i<4;i++)
    #pragma unroll
    for (int j=0;j<4;j++) acc[i][j] = (f32x4){0.f,0.f,0.f,0.f};

  for (int k0=0; k0<K; k0+=64){
    __syncthreads();
    #pragma unroll
    for (int s=0;s<9;s++) gload16(srcp[s] + k0, ldsp[s]);
    __syncthreads();
    #pragma unroll
    for (int kk=0;kk<2;kk++){
      bf16x8 af[4], bfr[4];
      #pragma unroll
      for (int m=0;m<4;m++) af[m]  = *(const bf16x8*)&As[wr + m*16 + l15][kk*32 + lq*8];
      #pragma unroll
      for (int n=0;n<4;n++) bfr[n] = *(const bf16x8*)&Bs[wc + n*16 + l15][kk*32 + lq*8];
      #pragma unroll
      for (int m=0;m<4;m++)
        #pragma unroll
        for (int n=0;n<4;n++)
          acc[m][n] = __builtin_amdgcn_mfma_f32_16x16x32_bf16(af[m], bfr[n], acc[m][n], 0,0,0);
    }
  }

  char* outz = (char*)outp + bStrideOutBytes * (size_t)blockIdx.z;
  #pragma unroll
  for (int n=0;n<4;n++){
    int col = colB0 + wc + n*16 + l15;
    float bv = BIAS ? bias[col] : 0.f;
    #pragma unroll
    for (int m=0;m<4;m++){
      #pragma unroll
      for (int r=0;r<4;r++){
        int row = rowA0 + wr + m*16 + lq*4 + r;
        float v = acc[m][n][r] + bv;
        if (RELU) v = v>0.f ? v : 0.f;
        if (OUTBF) ((u16*)outz)[(size_t)row*N + col] = f2bf(v);
        else       ((float*)outz)[(size_t)row*N + col] = v;
      }
    }
  }
}

// ---------------------------------------------------------------- GRU: 16 blocks x 32 cols, MALL-coherent h/flags (sc0 sc1)
__global__ __launch_bounds__(256) void gru_k(const float* __restrict__ gx,
                                             const u16* __restrict__ WhT,
                                             u16* __restrict__ hout,
                                             u16* __restrict__ hbuf,
                                             int* __restrict__ flags, int T, int base)
{
  __shared__ __align__(16) u16 Ws[96][520];
  int tid = threadIdx.x, lane = tid & 63, wv = tid >> 6;
  int l15 = lane & 15, lq = lane >> 4;
  int U0 = blockIdx.x*GCOLS;
  for (int i = tid; i < 96*64; i += 256){
    int lc = i >> 6, kk = (i & 63)*8;
    int g = lc >> 5, j = lc & 31;
    *(bf16x8*)&Ws[lc][kk] = *(const bf16x8*)(WhT + ((size_t)(g*512 + U0 + j))*512 + kk);
  }
  float hreg[2][4] = {{0.f,0.f,0.f,0.f},{0.f,0.f,0.f,0.f}};
  int row0 = wv*16;
  __syncthreads();

  float gxr[3][2][4];
  #pragma unroll
  for (int r=0;r<4;r++){
    const float* gp = gx + ((size_t)(row0 + lq*4 + r))*1536;
    #pragma unroll
    for (int nf=0;nf<2;nf++){
      int u = U0 + nf*16 + l15;
      gxr[0][nf][r] = gp[u]; gxr[1][nf][r] = gp[512+u]; gxr[2][nf][r] = gp[1024+u];
    }
  }

  for (int t=0; t<T; ++t){
    f32x4 acc[3][2];
    #pragma unroll
    for (int g=0;g<3;g++)
      #pragma unroll
      for (int nf=0;nf<2;nf++) acc[g][nf] = (f32x4){0.f,0.f,0.f,0.f};

    if (t > 0){
      if (wv == 0){
        const int* fp = flags + (lane & 15)*32;
        int target = base + t;
        while (true){
          int v;
          asm volatile("global_load_dword %0, %1, off sc0 sc1\n\ts_waitcnt vmcnt(0)"
                       : "=v"(v) : "v"(fp) : "memory");
          if (__all(v >= target)) break;
        }
      }
      __syncthreads();
      const u16* hsrc = hbuf + (size_t)(t&1)*(64*512);
      const u16* hp = hsrc + (size_t)(row0 + l15)*512 + lq*8;
      bf16x8 af[16];
      asm volatile(
        "global_load_dwordx4 %0,  %16, off sc0 sc1\n\t"
        "global_load_dwordx4 %1,  %16, off offset:64 sc0 sc1\n\t"
        "global_load_dwordx4 %2,  %16, off offset:128 sc0 sc1\n\t"
        "global_load_dwordx4 %3,  %16, off offset:192 sc0 sc1\n\t"
        "global_load_dwordx4 %4,  %16, off offset:256 sc0 sc1\n\t"
        "global_load_dwordx4 %5,  %16, off offset:320 sc0 sc1\n\t"
        "global_load_dwordx4 %6,  %16, off offset:384 sc0 sc1\n\t"
        "global_load_dwordx4 %7,  %16, off offset:448 sc0 sc1\n\t"
        "global_load_dwordx4 %8,  %16, off offset:512 sc0 sc1\n\t"
        "global_load_dwordx4 %9,  %16, off offset:576 sc0 sc1\n\t"
        "global_load_dwordx4 %10, %16, off offset:640 sc0 sc1\n\t"
        "global_load_dwordx4 %11, %16, off offset:704 sc0 sc1\n\t"
        "global_load_dwordx4 %12, %16, off offset:768 sc0 sc1\n\t"
        "global_load_dwordx4 %13, %16, off offset:832 sc0 sc1\n\t"
        "global_load_dwordx4 %14, %16, off offset:896 sc0 sc1\n\t"
        "global_load_dwordx4 %15, %16, off offset:960 sc0 sc1"
        : "=v"(af[0]), "=v"(af[1]), "=v"(af[2]), "=v"(af[3]),
          "=v"(af[4]), "=v"(af[5]), "=v"(af[6]), "=v"(af[7]),
          "=v"(af[8]), "=v"(af[9]), "=v"(af[10]), "=v"(af[11]),
          "=v"(af[12]), "=v"(af[13]), "=v"(af[14]), "=v"(af[15])
        : "v"(hp) : "memory");
      asm volatile("s_waitcnt vmcnt(0)" ::: "memory");
      __builtin_amdgcn_sched_barrier(0);   // rule #18
      #pragma unroll
      for (int k=0;k<16;k++){
        #pragma unroll
        for (int g=0;g<3;g++){
          #pragma unroll
          for (int nf=0;nf<2;nf++){
            bf16x8 bf_ = *(const bf16x8*)&Ws[g*GCOLS + nf*16 + l15][k*32 + lq*8];
            acc[g][nf] = __builtin_amdgcn_mfma_f32_16x16x32_bf16(af[k], bf_, acc[g][nf], 0,0,0);
          }
        }
      }
    }

    u16* hdst = hbuf + (size_t)((t+1)&1)*(64*512);
    u16 hb[2][4];
    u32 hv[8];
    #pragma unroll
    for (int nf=0;nf<2;nf++){
      #pragma unroll
      for (int r=0;r<4;r++){
        float rg = 1.f/(1.f + __expf(-(acc[0][nf][r] + gxr[0][nf][r])));
        float zg = 1.f/(1.f + __expf(-(acc[1][nf][r] + gxr[1][nf][r])));
        float ng = tanhf(gxr[2][nf][r] + rg*acc[2][nf][r]);
        float hn = (1.f - zg)*ng + zg*hreg[nf][r];
        hreg[nf][r] = hn;
        hb[nf][r] = f2bf(hn);
        hv[nf*4+r] = hb[nf][r];
      }
    }
    {
      u16* sp_ = hdst + (size_t)(row0 + lq*4)*512 + U0 + l15;
      asm volatile(
        "global_store_short %8, %0, off sc0 sc1\n\t"
        "global_store_short %8, %1, off offset:1024 sc0 sc1\n\t"
        "global_store_short %8, %2, off offset:2048 sc0 sc1\n\t"
        "global_store_short %8, %3, off offset:3072 sc0 sc1\n\t"
        "global_store_short %8, %4, off offset:32 sc0 sc1\n\t"
        "global_store_short %8, %5, off offset:1056 sc0 sc1\n\t"
        "global_store_short %8, %6, off offset:2080 sc0 sc1\n\t"
        "global_store_short %8, %7, off offset:3104 sc0 sc1"
        :: "v"(hv[0]), "v"(hv[1]), "v"(hv[2]), "v"(hv[3]),
           "v"(hv[4]), "v"(hv[5]), "v"(hv[6]), "v"(hv[7]), "v"(sp_)
        : "memory");
    }
    asm volatile("s_waitcnt vmcnt(0)" ::: "memory");
    __syncthreads();
    if (tid == 0){
      int val = base + t + 1;
      asm volatile("global_store_dword %0, %1, off sc0 sc1"
                   :: "v"(flags + blockIdx.x*32), "v"(val) : "memory");
    }
    #pragma unroll
    for (int nf=0;nf<2;nf++){
      int u = U0 + nf*16 + l15;
      #pragma unroll
      for (int r=0;r<4;r++)
        hout[(((size_t)(row0 + lq*4 + r))*T + t)*512 + u] = hb[nf][r];
    }
    if (t+1 < T){
      #pragma unroll
      for (int r=0;r<4;r++){
        const float* gp = gx + ((size_t)(t+1)*64 + row0 + lq*4 + r)*1536;
        #pragma unroll
        for (int nf=0;nf<2;nf++){
          int u = U0 + nf*16 + l15;
          gxr[0][nf][r] = gp[u]; gxr[1][nf][r] = gp[512+u]; gxr[2][nf][r] = gp[1024+u];
        }
      }
    }
  }
}

// ---------------------------------------------------------------- conv via lookup table + cond + bias + relu
__global__ __launch_bounds__(256) void conv_k(const int* __restrict__ seq, const u16* __restrict__ Ttab,
  const u16* __restrict__ cond, const float* __restrict__ bconv, u16* __restrict__ h1, int g0)
{
  int sub = threadIdx.x >> 6, lane = threadIdx.x & 63;
  int lrow = blockIdx.x*4 + sub;
  int g = g0 + lrow;
  int b = g >> 11, t = g & 2047;
  const int* sp = seq + b*SEQ_ + 48 + t;
  int o = lane*8;
  float a[8];
  bf16x8 cs = *(const bf16x8*)(cond + (size_t)lrow*512 + o);
  #pragma unroll
  for (int j=0;j<8;j++) a[j] = bf2f((u16)cs[j]) + bconv[o+j];
  #pragma unroll
  for (int w=0;w<16;w++){
    int q = sp[w];
    bf16x8 tv = *(const bf16x8*)(Ttab + ((size_t)(w*256+q))*512 + o);
    #pragma unroll
    for (int j=0;j<8;j++) a[j] += bf2f((u16)tv[j]);
  }
  u16 res[8];
  #pragma unroll
  for (int j=0;j<8;j++) res[j] = f2bf(a[j] > 0.f ? a[j] : 0.f);
  *(bf16x8*)(h1 + (size_t)lrow*512 + o) = *(const bf16x8*)res;
}

// ---------------------------------------------------------------- launcher
extern "C" void kernel_launch(void* const* d_in, const int* in_sizes, int n_in,
                              void* d_out, int out_size, void* d_ws, size_t ws_size,
                              hipStream_t stream)
{
  (void)in_sizes; (void)n_in; (void)out_size;
  const int*   seq     = (const int*)d_in[0];
  const float* noise   = (const float*)d_in[2];
  const float* W_in_top= (const float*)d_in[3];
  const float* W_hf_top= (const float*)d_in[4];
  const float* b_in_top= (const float*)d_in[5];
  const float* Wx_top  = (const float*)d_in[6];
  const float* bx_top  = (const float*)d_in[7];
  const float* Wh_top  = (const float*)d_in[8];
  const float* W_up_top= (const float*)d_in[9];
  const float* W_in_bot= (const float*)d_in[10];
  const float* W_hf_bot= (const float*)d_in[11];
  const float* b_in_bot= (const float*)d_in[12];
  const float* Wx_bot  = (const float*)d_in[13];
  const float* bx_bot  = (const float*)d_in[14];
  const float* Wh_bot  = (const float*)d_in[15];
  const float* W_up_bot= (const float*)d_in[16];
  const float* embed   = (const float*)d_in[17];
  const float* W_conv  = (const float*)d_in[18];
  const float* b_conv  = (const float*)d_in[19];
  const float* W1      = (const float*)d_in[20];
  const float* b1      = (const float*)d_in[21];
  const float* W2      = (const float*)d_in[22];
  const float* b2      = (const float*)d_in[23];
  const float* W_out   = (const float*)d_in[24];
  const float* b_out   = (const float*)d_in[25];
  float* outF = (float*)d_out;
  char* ws = (char*)d_ws;

  size_t off = 0;
  auto alloc = [&](size_t bytes){ size_t o = off; off = (off + bytes + 255) & ~(size_t)255; return o; };
  const size_t oHF   = alloc((size_t)2048*16*4);
  const size_t oWxtT = alloc((size_t)1536*512*2);
  const size_t oWhtT = alloc((size_t)1536*512*2);
  const size_t oWxtB = alloc((size_t)1536*512*2);
  const size_t oWhtB = alloc((size_t)1536*512*2);
  const size_t oWupT = alloc((size_t)2048*512*2);
  const size_t oWupB = alloc((size_t)8192*512*2);
  const size_t oW1T  = alloc((size_t)512*512*2);
  const size_t oW2T  = alloc((size_t)512*512*2);
  const size_t oWoT  = alloc((size_t)256*512*2);
  const size_t oEmb  = alloc((size_t)256*256*2);
  const size_t oWcT  = alloc((size_t)16*512*256*2);
  const size_t oTtab = alloc((size_t)16*256*512*2);
  const size_t oHbot = alloc((size_t)8192*512*2);
  const size_t oGruH = alloc((size_t)2*64*512*2);   // h double buffer
  const size_t oBar  = alloc(4096);                 // per-block flag cachelines
  const size_t SCR   = off;
  const size_t MB = 1u<<20;
  const size_t oInpT = SCR;
  const size_t oGxT  = SCR + 4*MB;
  const size_t oHtop = SCR;
  const size_t oCond = SCR + 4*MB;
  const size_t oInpB = SCR + 24*MB;
  const size_t oGxB  = SCR + 36*MB;

  // adaptive tail chunking: pick biggest chunk whose 3 intermediates fit in ws
  size_t avail = (ws_size > SCR) ? ws_size - SCR : 0;
  int nch;
  if      (avail >= (size_t)412*MB) nch = 1;
  else if (avail >= (size_t)208*MB) nch = 2;
  else                              nch = 4;
  const int    HR = 8192/nch;          // hbot rows per chunk
  const int    SR = HR*16;             // sample rows per chunk
  const size_t CB = (size_t)SR*512*2;  // bytes per intermediate
  const size_t oCndC = SCR;
  const size_t oH1   = SCR + CB;
  const size_t oH2   = SCR + 2*CB;
  const size_t oH3   = oCndC;          // CndC dead after conv

  dim3 b256(256), b512(512), b64(64);

  // ---- weight prep: one merged dispatch
  PrepArgs pa;
  pa.wxt=Wx_top;  pa.wht=Wh_top;  pa.wxb=Wx_bot;  pa.whb=Wh_bot;
  pa.wupt=W_up_top; pa.wupb=W_up_bot; pa.w1=W1; pa.w2=W2; pa.wo=W_out;
  pa.wc=W_conv; pa.emb=embed;
  pa.owxt=(u16*)(ws+oWxtT); pa.owht=(u16*)(ws+oWhtT); pa.owxb=(u16*)(ws+oWxtB); pa.owhb=(u16*)(ws+oWhtB);
  pa.owupt=(u16*)(ws+oWupT); pa.owupb=(u16*)(ws+oWupB); pa.ow1=(u16*)(ws+oW1T); pa.ow2=(u16*)(ws+oW2T);
  pa.owo=(u16*)(ws+oWoT); pa.owc=(u16*)(ws+oWcT); pa.oemb=(u16*)(ws+oEmb);
  prep_k<<<dim3(11136),b256,0,stream>>>(pa);

  // ---- hf features
  hf_k<<<dim3(2048),b64,0,stream>>>(seq, noise, (float*)(ws+oHF));

  // ---- barrier flags init (flags carry across both GRUs via `base`)
  hipMemsetAsync(ws+oBar, 0, 4096, stream);

  // ---- top frame-level path
  inp_top_k<<<dim3(2048),b512,0,stream>>>(seq,(const float*)(ws+oHF),W_in_top,W_hf_top,b_in_top,(u16*)(ws+oInpT));
  gemm_bt<1,0,0><<<dim3(16,12,1),b256,0,stream>>>((const u16*)(ws+oInpT),(const u16*)(ws+oWxtT),bx_top,(void*)(ws+oGxT),2048,1536,512,0,0);
  gru_k<<<dim3(GBLK),b256,0,stream>>>((const float*)(ws+oGxT),(const u16*)(ws+oWhtT),(u16*)(ws+oHtop),(u16*)(ws+oGruH),(int*)(ws+oBar),32,0);
  gemm_bt<0,0,0><<<dim3(16,16,1),b256,0,stream>>>((const u16*)(ws+oHtop),(const u16*)(ws+oWupT),nullptr,(void*)(ws+oCond),2048,2048,512,0,0);

  // ---- bottom frame-level path
  inp_bot_k<<<dim3(8192),b512,0,stream>>>(seq,(const float*)(ws+oHF),(const float*)(ws+oCond),W_in_bot,W_hf_bot,b_in_bot,(u16*)(ws+oInpB));
  gemm_bt<1,0,0><<<dim3(64,12,1),b256,0,stream>>>((const u16*)(ws+oInpB),(const u16*)(ws+oWxtB),bx_bot,(void*)(ws+oGxB),8192,1536,512,0,0);
  gru_k<<<dim3(GBLK),b256,0,stream>>>((const float*)(ws+oGxB),(const u16*)(ws+oWhtB),(u16*)(ws+oHbot),(u16*)(ws+oGruH),(int*)(ws+oBar),128,32);

  // ---- conv lookup table T[w] = embed @ W_conv[w]
  gemm_bt<0,0,1><<<dim3(2,4,16),b256,0,stream>>>((const u16*)(ws+oEmb),(const u16*)(ws+oWcT),nullptr,(void*)(ws+oTtab),
                                                 256,512,256,(size_t)512*256,(size_t)256*512*2);

  // ---- sample-level tail, nch chunks of SR rows each
  for (int c=0;c<nch;c++){
    const u16* hbc = (const u16*)(ws+oHbot) + (size_t)c*HR*512;
    gemm_bt<0,0,1><<<dim3(HR/128,64,1),b256,0,stream>>>(hbc,(const u16*)(ws+oWupB),nullptr,(void*)(ws+oCndC),HR,8192,512,0,0);
    conv_k<<<dim3(SR/4),b256,0,stream>>>(seq,(const u16*)(ws+oTtab),(const u16*)(ws+oCndC),b_conv,(u16*)(ws+oH1),c*SR);
    gemm_bt<1,1,1><<<dim3(SR/128,4,1),b256,0,stream>>>((const u16*)(ws+oH1),(const u16*)(ws+oW1T),b1,(void*)(ws+oH2),SR,512,512,0,0);
    gemm_bt<1,1,1><<<dim3(SR/128,4,1),b256,0,stream>>>((const u16*)(ws+oH2),(const u16*)(ws+oW2T),b2,(void*)(ws+oH3),SR,512,512,0,0);
    gemm_bt<1,0,0><<<dim3(SR/128,2,1),b256,0,stream>>>((const u16*)(ws+oH3),(const u16*)(ws+oWoT),b_out,(void*)(outF + (size_t)c*SR*256),SR,256,512,0,0);
  }
}